// Round 8
// baseline (89.856 us; speedup 1.0000x reference)
//
#include <hip/hip_runtime.h>
#include <math.h>

// 10-qubit real-amplitude circuit simulator, batch 16384, depth 8.
// Layout: 32 lanes per batch element (index bits [4:0] = lane&31),
//         32 scalar float VGPRs per lane (index bits [9:5] = register index).
// Qubit q <-> index bit (9-q): q0..q4 -> reg bits 4..0 ; q5..q9 -> lane 4..0.
// 2 elements per wave (lane bit 5 selects element), 8 per 256-thread block.
//
// Per layer:
//  1. reg-reg CNOT swaps (0,1),(2,3) — pure renames
//  2. fused cross-lane CNOTs (4,5),(6,7),(8,9),(5,6),(7,8): ONE ds_bpermute
//     per scalar; (4,5) control = reg b0 -> odd-r addr = addrE ^ 64
//     (must precede (3,4), which modifies reg b0)
//  3. reg-reg CNOT swaps (1,2),(3,4) — pure renames
//  4. RY q0..q4 in-register; q5 via ds_swizzle xor16; q6 via DPP row_ror:8;
//     q7 via ds_swizzle xor4; q8/q9 via DPP quad_perm

// ---- cross-lane helpers -------------------------------------------------
template<int CTRL>
__device__ __forceinline__ float dpp_mov(float x) {
  int i = __builtin_bit_cast(int, x);
  i = __builtin_amdgcn_update_dpp(i, i, CTRL, 0xf, 0xf, true);
  return __builtin_bit_cast(float, i);
}
__device__ __forceinline__ float xl1(float x) { return dpp_mov<0xB1>(x); }   // lane^1
__device__ __forceinline__ float xl2(float x) { return dpp_mov<0x4E>(x); }   // lane^2
__device__ __forceinline__ float xl8(float x) { return dpp_mov<0x128>(x); }  // row_ror:8 == lane^8
template<int PAT>
__device__ __forceinline__ float swz(float x) {  // ds_swizzle BitMode
  int i = __builtin_amdgcn_ds_swizzle(__builtin_bit_cast(int, x), PAT);
  return __builtin_bit_cast(float, i);
}
__device__ __forceinline__ float xl4(float x)  { return swz<0x101F>(x); }    // lane^4
__device__ __forceinline__ float xl16(float x) { return swz<0x401F>(x); }    // lane^16
__device__ __forceinline__ float bperm(int addr, float x) {
  int i = __builtin_amdgcn_ds_bpermute(addr, __builtin_bit_cast(int, x));
  return __builtin_bit_cast(float, i);
}
__device__ __forceinline__ float red32(float x) {
  x += xl1(x); x += xl2(x); x += xl4(x); x += xl8(x); x += xl16(x); return x;
}

// ---- RY on a register-bit qubit: pairs (r, r|M) -------------------------
template<int M>
__device__ __forceinline__ void ry_reg(float* v, float c, float s) {
  #pragma unroll
  for (int r = 0; r < 32; ++r) {
    if ((r & M) == 0) {
      float s0 = v[r], s1 = v[r + M];
      v[r]     = fmaf(c, s0, -(s * s1));
      v[r + M] = fmaf(s, s0,  c * s1);
    }
  }
}

// ---- one level of the sum/diff tree -------------------------------------
template<int L2>
__device__ __forceinline__ float tree_level(float* v) {
  float a = 0.f, b = 0.f;
  #pragma unroll
  for (int j = 0; j < L2; ++j) {
    float e = v[2 * j], o = v[2 * j + 1];
    if (j & 1) b += e - o; else a += e - o;
    v[j] = e + o;
  }
  return a + b;
}

__global__ __launch_bounds__(256, 8) void circuit_kernel(
    const float* __restrict__ x, const float* __restrict__ params,
    float* __restrict__ out) {
  __shared__ float csh[160];  // cos/sin of pi*tanh(param)/2, [l*20 + 2q {+1}]

  const int tid  = threadIdx.x;
  const int wv   = tid >> 6;
  const int lane = tid & 63;
  const int h    = lane >> 5;   // element within wave (0..1)
  const int l5   = lane & 31;   // lane within group = index bits [4:0]
  const long elem = (long)blockIdx.x * 8 + wv * 2 + h;

  if (tid < 80) {
    float th = 1.57079632679489662f * tanhf(params[tid]);  // (pi*tanh)/2
    csh[2 * tid]     = cosf(th);
    csh[2 * tid + 1] = sinf(th);
  }

  // bpermute pull map (inverse of push (4,5),(6,7),(8,9),(5,6),(7,8)):
  //   m = l5; b1^=b2; b3^=b4; b0^=b1; b2^=b3; [odd r: b4^=1]
  int m = l5 ^ ((l5 & 4) >> 1);   // undo (7,8)
  m ^= (m & 16) >> 1;             // undo (5,6)
  m ^= (m & 2) >> 1;              // undo (8,9)
  m ^= (m & 8) >> 1;              // undo (6,7)
  const int addrE = ((lane & 32) | m) << 2;  // even-r source (byte addr)
  const int addrO = addrE ^ 64;              // odd r: lane b4 additionally flips

  // ---- load: 784 = 24*32 + 16, stride-32 per lane ------------------------
  float v[32];
  const float* xb = x + elem * 784 + l5;
  #pragma unroll
  for (int k = 0; k < 24; ++k) v[k] = xb[k * 32];
  v[24] = (l5 < 16) ? xb[768] : 0.f;
  #pragma unroll
  for (int k = 25; k < 32; ++k) v[k] = 0.f;

  // ---- L2 normalize ------------------------------------------------------
  float nn = 0.f;
  #pragma unroll
  for (int k = 0; k < 25; ++k) nn = fmaf(v[k], v[k], nn);
  nn = red32(nn);
  float scl = 1.0f / sqrtf(nn);
  #pragma unroll
  for (int k = 0; k < 25; ++k) v[k] *= scl;

  __syncthreads();   // csh ready

  // ---- 8 layers ----------------------------------------------------------
  #pragma unroll 1
  for (int l = 0; l < 8; ++l) {
    // 1. reg-reg swaps for CNOT (0,1),(2,3)
    #pragma unroll
    for (int r = 0; r < 32; ++r) if ((r & 24) == 16) { float t = v[r]; v[r] = v[r + 8]; v[r + 8] = t; } // (0,1)
    #pragma unroll
    for (int r = 0; r < 32; ++r) if ((r & 6) == 4) { float t = v[r]; v[r] = v[r + 2]; v[r + 2] = t; }   // (2,3)

    // 2. fused cross-lane CNOTs: one bpermute per scalar
    #pragma unroll
    for (int r = 0; r < 32; r += 2) {
      v[r]     = bperm(addrE, v[r]);
      v[r + 1] = bperm(addrO, v[r + 1]);
    }

    // 3. reg-reg swaps for CNOT (1,2),(3,4)
    #pragma unroll
    for (int r = 0; r < 32; ++r) if ((r & 12) == 8) { float t = v[r]; v[r] = v[r + 4]; v[r + 4] = t; }  // (1,2)
    #pragma unroll
    for (int r = 0; r < 32; ++r) if ((r & 3) == 2) { float t = v[r]; v[r] = v[r + 1]; v[r + 1] = t; }   // (3,4)

    // 4. RY gates
    const float* cl = &csh[l * 20];
    ry_reg<16>(v, cl[0],  cl[1]);    // q0
    ry_reg< 8>(v, cl[2],  cl[3]);    // q1
    ry_reg< 4>(v, cl[4],  cl[5]);    // q2
    ry_reg< 2>(v, cl[6],  cl[7]);    // q3
    ry_reg< 1>(v, cl[8],  cl[9]);    // q4
    // q5 (lane bit 4) via ds_swizzle xor16
    {
      float c = cl[10], s = cl[11];
      float sn = (lane & 16) ? s : -s;
      #pragma unroll
      for (int r = 0; r < 32; ++r) { float p = xl16(v[r]); v[r] = fmaf(c, v[r], sn * p); }
    }
    // q6 (lane bit 3) via DPP row_ror:8
    {
      float c = cl[12], s = cl[13];
      float sn = (lane & 8) ? s : -s;
      #pragma unroll
      for (int r = 0; r < 32; ++r) { float p = xl8(v[r]); v[r] = fmaf(c, v[r], sn * p); }
    }
    // q7 (lane bit 2) via ds_swizzle xor4
    {
      float c = cl[14], s = cl[15];
      float sn = (lane & 4) ? s : -s;
      #pragma unroll
      for (int r = 0; r < 32; ++r) { float p = xl4(v[r]); v[r] = fmaf(c, v[r], sn * p); }
    }
    // q8 (lane bit 1) via DPP xor2
    {
      float c = cl[16], s = cl[17];
      float sn = (lane & 2) ? s : -s;
      #pragma unroll
      for (int r = 0; r < 32; ++r) { float p = xl2(v[r]); v[r] = fmaf(c, v[r], sn * p); }
    }
    // q9 (lane bit 0) via DPP xor1
    {
      float c = cl[18], s = cl[19];
      float sn = (lane & 1) ? s : -s;
      #pragma unroll
      for (int r = 0; r < 32; ++r) { float p = xl1(v[r]); v[r] = fmaf(c, v[r], sn * p); }
    }
  }

  // ---- expectation values ------------------------------------------------
  float z[10];
  #pragma unroll
  for (int r = 0; r < 32; ++r) v[r] *= v[r];   // probabilities
  z[4] = red32(tree_level<16>(v));
  z[3] = red32(tree_level< 8>(v));
  z[2] = red32(tree_level< 4>(v));
  z[1] = red32(tree_level< 2>(v));
  z[0] = red32(tree_level< 1>(v));
  float W = v[0];  // per-lane total probability
  // lane-bit qubits: signed reductions over the 32-lane group
  { float u = W + xl1(W); u += xl2(u); u += xl4(u); u += xl8(u);  float t = u - xl16(u); z[5] = (lane & 16) ? -t : t; }
  { float u = W + xl1(W); u += xl2(u); u += xl4(u); u += xl16(u); float t = u - xl8(u);  z[6] = (lane & 8)  ? -t : t; }
  { float u = W + xl1(W); u += xl2(u); u += xl8(u); u += xl16(u); float t = u - xl4(u);  z[7] = (lane & 4)  ? -t : t; }
  { float u = W + xl1(W); u += xl4(u); u += xl8(u); u += xl16(u); float t = u - xl2(u);  z[8] = (lane & 2)  ? -t : t; }
  { float u = W + xl2(W); u += xl4(u); u += xl8(u); u += xl16(u); float t = u - xl1(u);  z[9] = (lane & 1)  ? -t : t; }

  // ---- store: lane l5 (<10) writes column l5 -----------------------------
  float o = z[0];
  #pragma unroll
  for (int j = 1; j < 10; ++j) o = (l5 == j) ? z[j] : o;
  if (l5 < 10) out[elem * 10 + l5] = o;
}

extern "C" void kernel_launch(void* const* d_in, const int* in_sizes, int n_in,
                              void* d_out, int out_size, void* d_ws, size_t ws_size,
                              hipStream_t stream) {
  const float* x      = (const float*)d_in[0];   // [16384, 784]
  const float* params = (const float*)d_in[1];   // [8, 10]
  float* out          = (float*)d_out;           // [16384, 10]
  (void)d_ws; (void)ws_size; (void)in_sizes; (void)n_in; (void)out_size;
  // 16384 elements / 8 per block (2 per wave x 4 waves)
  circuit_kernel<<<2048, 256, 0, stream>>>(x, params, out);
}

// Round 9
// 73.839 us; speedup vs baseline: 1.2169x; 1.2169x over previous
//
#include <hip/hip_runtime.h>
#include <math.h>

// 10-qubit real-amplitude circuit simulator, batch 16384, depth 8.
// Layout: 32 lanes per batch element (index bits [4:0] = lane&31),
//         32 scalar float VGPRs per lane (index bits [9:5] = register index).
// Qubit q <-> index bit (9-q): q0..q4 -> reg bits 4..0 ; q5..q9 -> lane 4..0.
// 2 elements per wave (lane bit 5 selects element), 8 per 256-thread block.
//
// vs round 8 (two changes, same gate order / index maps):
//  - __launch_bounds__(256,6): 85-VGPR cap instead of 64 -> no forced spill;
//    HW residency still reaches 8/SIMD if actual alloc <= 64.
//  - 8-layer loop FULLY UNROLLED: reg-reg CNOT swaps become pure SSA renames
//    (no back-edge mov churn), ~25% VALU-stream reduction.

// ---- cross-lane helpers -------------------------------------------------
template<int CTRL>
__device__ __forceinline__ float dpp_mov(float x) {
  int i = __builtin_bit_cast(int, x);
  i = __builtin_amdgcn_update_dpp(i, i, CTRL, 0xf, 0xf, true);
  return __builtin_bit_cast(float, i);
}
__device__ __forceinline__ float xl1(float x) { return dpp_mov<0xB1>(x); }   // lane^1
__device__ __forceinline__ float xl2(float x) { return dpp_mov<0x4E>(x); }   // lane^2
__device__ __forceinline__ float xl8(float x) { return dpp_mov<0x128>(x); }  // row_ror:8 == lane^8
template<int PAT>
__device__ __forceinline__ float swz(float x) {  // ds_swizzle BitMode
  int i = __builtin_amdgcn_ds_swizzle(__builtin_bit_cast(int, x), PAT);
  return __builtin_bit_cast(float, i);
}
__device__ __forceinline__ float xl4(float x)  { return swz<0x101F>(x); }    // lane^4
__device__ __forceinline__ float xl16(float x) { return swz<0x401F>(x); }    // lane^16
__device__ __forceinline__ float bperm(int addr, float x) {
  int i = __builtin_amdgcn_ds_bpermute(addr, __builtin_bit_cast(int, x));
  return __builtin_bit_cast(float, i);
}
__device__ __forceinline__ float red32(float x) {
  x += xl1(x); x += xl2(x); x += xl4(x); x += xl8(x); x += xl16(x); return x;
}

// ---- RY on a register-bit qubit: pairs (r, r|M) -------------------------
template<int M>
__device__ __forceinline__ void ry_reg(float* v, float c, float s) {
  #pragma unroll
  for (int r = 0; r < 32; ++r) {
    if ((r & M) == 0) {
      float s0 = v[r], s1 = v[r + M];
      v[r]     = fmaf(c, s0, -(s * s1));
      v[r + M] = fmaf(s, s0,  c * s1);
    }
  }
}

// ---- one level of the sum/diff tree -------------------------------------
template<int L2>
__device__ __forceinline__ float tree_level(float* v) {
  float a = 0.f, b = 0.f;
  #pragma unroll
  for (int j = 0; j < L2; ++j) {
    float e = v[2 * j], o = v[2 * j + 1];
    if (j & 1) b += e - o; else a += e - o;
    v[j] = e + o;
  }
  return a + b;
}

__global__ __launch_bounds__(256, 6) void circuit_kernel(
    const float* __restrict__ x, const float* __restrict__ params,
    float* __restrict__ out) {
  __shared__ float csh[160];  // cos/sin of pi*tanh(param)/2, [l*20 + 2q {+1}]

  const int tid  = threadIdx.x;
  const int wv   = tid >> 6;
  const int lane = tid & 63;
  const int h    = lane >> 5;   // element within wave (0..1)
  const int l5   = lane & 31;   // lane within group = index bits [4:0]
  const long elem = (long)blockIdx.x * 8 + wv * 2 + h;

  if (tid < 80) {
    float th = 1.57079632679489662f * tanhf(params[tid]);  // (pi*tanh)/2
    csh[2 * tid]     = cosf(th);
    csh[2 * tid + 1] = sinf(th);
  }

  // bpermute pull map (inverse of push (4,5),(6,7),(8,9),(5,6),(7,8)):
  //   m = l5; b1^=b2; b3^=b4; b0^=b1; b2^=b3; [odd r: b4^=1]
  int m = l5 ^ ((l5 & 4) >> 1);   // undo (7,8)
  m ^= (m & 16) >> 1;             // undo (5,6)
  m ^= (m & 2) >> 1;              // undo (8,9)
  m ^= (m & 8) >> 1;              // undo (6,7)
  const int addrE = ((lane & 32) | m) << 2;  // even-r source (byte addr)
  const int addrO = addrE ^ 64;              // odd r: lane b4 additionally flips

  // ---- load: 784 = 24*32 + 16, stride-32 per lane ------------------------
  float v[32];
  const float* xb = x + elem * 784 + l5;
  #pragma unroll
  for (int k = 0; k < 24; ++k) v[k] = xb[k * 32];
  v[24] = (l5 < 16) ? xb[768] : 0.f;
  #pragma unroll
  for (int k = 25; k < 32; ++k) v[k] = 0.f;

  // ---- L2 normalize ------------------------------------------------------
  float nn = 0.f;
  #pragma unroll
  for (int k = 0; k < 25; ++k) nn = fmaf(v[k], v[k], nn);
  nn = red32(nn);
  float scl = 1.0f / sqrtf(nn);
  #pragma unroll
  for (int k = 0; k < 25; ++k) v[k] *= scl;

  __syncthreads();   // csh ready

  // ---- 8 layers, FULLY UNROLLED (swaps become free SSA renames) ----------
  #pragma unroll
  for (int l = 0; l < 8; ++l) {
    // 1. reg-reg swaps for CNOT (0,1),(2,3)
    #pragma unroll
    for (int r = 0; r < 32; ++r) if ((r & 24) == 16) { float t = v[r]; v[r] = v[r + 8]; v[r + 8] = t; } // (0,1)
    #pragma unroll
    for (int r = 0; r < 32; ++r) if ((r & 6) == 4) { float t = v[r]; v[r] = v[r + 2]; v[r + 2] = t; }   // (2,3)

    // 2. fused cross-lane CNOTs (4,5),(6,7),(8,9),(5,6),(7,8): one bperm/scalar
    #pragma unroll
    for (int r = 0; r < 32; r += 2) {
      v[r]     = bperm(addrE, v[r]);
      v[r + 1] = bperm(addrO, v[r + 1]);
    }

    // 3. reg-reg swaps for CNOT (1,2),(3,4)
    #pragma unroll
    for (int r = 0; r < 32; ++r) if ((r & 12) == 8) { float t = v[r]; v[r] = v[r + 4]; v[r + 4] = t; }  // (1,2)
    #pragma unroll
    for (int r = 0; r < 32; ++r) if ((r & 3) == 2) { float t = v[r]; v[r] = v[r + 1]; v[r + 1] = t; }   // (3,4)

    // 4. RY gates
    const float* cl = &csh[l * 20];
    ry_reg<16>(v, cl[0],  cl[1]);    // q0
    ry_reg< 8>(v, cl[2],  cl[3]);    // q1
    ry_reg< 4>(v, cl[4],  cl[5]);    // q2
    ry_reg< 2>(v, cl[6],  cl[7]);    // q3
    ry_reg< 1>(v, cl[8],  cl[9]);    // q4
    // q5 (lane bit 4) via ds_swizzle xor16
    {
      float c = cl[10], s = cl[11];
      float sn = (lane & 16) ? s : -s;
      #pragma unroll
      for (int r = 0; r < 32; ++r) { float p = xl16(v[r]); v[r] = fmaf(c, v[r], sn * p); }
    }
    // q6 (lane bit 3) via DPP row_ror:8
    {
      float c = cl[12], s = cl[13];
      float sn = (lane & 8) ? s : -s;
      #pragma unroll
      for (int r = 0; r < 32; ++r) { float p = xl8(v[r]); v[r] = fmaf(c, v[r], sn * p); }
    }
    // q7 (lane bit 2) via ds_swizzle xor4
    {
      float c = cl[14], s = cl[15];
      float sn = (lane & 4) ? s : -s;
      #pragma unroll
      for (int r = 0; r < 32; ++r) { float p = xl4(v[r]); v[r] = fmaf(c, v[r], sn * p); }
    }
    // q8 (lane bit 1) via DPP xor2
    {
      float c = cl[16], s = cl[17];
      float sn = (lane & 2) ? s : -s;
      #pragma unroll
      for (int r = 0; r < 32; ++r) { float p = xl2(v[r]); v[r] = fmaf(c, v[r], sn * p); }
    }
    // q9 (lane bit 0) via DPP xor1
    {
      float c = cl[18], s = cl[19];
      float sn = (lane & 1) ? s : -s;
      #pragma unroll
      for (int r = 0; r < 32; ++r) { float p = xl1(v[r]); v[r] = fmaf(c, v[r], sn * p); }
    }
  }

  // ---- expectation values ------------------------------------------------
  float z[10];
  #pragma unroll
  for (int r = 0; r < 32; ++r) v[r] *= v[r];   // probabilities
  z[4] = red32(tree_level<16>(v));
  z[3] = red32(tree_level< 8>(v));
  z[2] = red32(tree_level< 4>(v));
  z[1] = red32(tree_level< 2>(v));
  z[0] = red32(tree_level< 1>(v));
  float W = v[0];  // per-lane total probability
  // lane-bit qubits: signed reductions over the 32-lane group
  { float u = W + xl1(W); u += xl2(u); u += xl4(u); u += xl8(u);  float t = u - xl16(u); z[5] = (lane & 16) ? -t : t; }
  { float u = W + xl1(W); u += xl2(u); u += xl4(u); u += xl16(u); float t = u - xl8(u);  z[6] = (lane & 8)  ? -t : t; }
  { float u = W + xl1(W); u += xl2(u); u += xl8(u); u += xl16(u); float t = u - xl4(u);  z[7] = (lane & 4)  ? -t : t; }
  { float u = W + xl1(W); u += xl4(u); u += xl8(u); u += xl16(u); float t = u - xl2(u);  z[8] = (lane & 2)  ? -t : t; }
  { float u = W + xl2(W); u += xl4(u); u += xl8(u); u += xl16(u); float t = u - xl1(u);  z[9] = (lane & 1)  ? -t : t; }

  // ---- store: lane l5 (<10) writes column l5 -----------------------------
  float o = z[0];
  #pragma unroll
  for (int j = 1; j < 10; ++j) o = (l5 == j) ? z[j] : o;
  if (l5 < 10) out[elem * 10 + l5] = o;
}

extern "C" void kernel_launch(void* const* d_in, const int* in_sizes, int n_in,
                              void* d_out, int out_size, void* d_ws, size_t ws_size,
                              hipStream_t stream) {
  const float* x      = (const float*)d_in[0];   // [16384, 784]
  const float* params = (const float*)d_in[1];   // [8, 10]
  float* out          = (float*)d_out;           // [16384, 10]
  (void)d_ws; (void)ws_size; (void)in_sizes; (void)n_in; (void)out_size;
  // 16384 elements / 8 per block (2 per wave x 4 waves)
  circuit_kernel<<<2048, 256, 0, stream>>>(x, params, out);
}